// Round 7
// baseline (271.848 us; speedup 1.0000x reference)
//
#include <hip/hip_runtime.h>
#include <cstdint>
#include <cstddef>

#define B_ 8
#define N_ 10000
#define C_ 64
#define DIM_ 256
#define E_ 160000
#define ROWS_ (B_ * N_)            // 80000
#define OUT_OFF_ ((size_t)B_ * N_ * C_)  // 5,120,000
#define NBLK_ 157                  // ceil(N/64)

typedef unsigned short u16;
typedef unsigned int u32;
typedef __attribute__((ext_vector_type(8))) short bf16x8;
typedef __attribute__((ext_vector_type(4))) float f32x4;

#define HSTRIDE 268  // u16; 134 dwords == 6 mod 32 -> <=4-way on b128 A-reads

__device__ __forceinline__ u16 f2bf(float f) {
    unsigned int u = __float_as_uint(f);
    unsigned int r = u + 0x7FFF + ((u >> 16) & 1);  // RNE
    return (u16)(r >> 16);
}
__device__ __forceinline__ float bf2f(u32 h) {      // low 16 bits hold bf16
    return __uint_as_float(h << 16);
}
__device__ __forceinline__ unsigned int pack2(float a, float b) {
    return (unsigned int)f2bf(a) | ((unsigned int)f2bf(b) << 16);
}
__device__ __forceinline__ float swish_f(float v, float sp) {
    float e = __expf(-v * sp);
    float s = __builtin_amdgcn_rcpf(1.0f + e);
    return v * s * (1.0f / 1.1f);
}

#define MFMA16(a, b, c) __builtin_amdgcn_mfma_f32_16x16x32_bf16(a, b, c, 0, 0, 0)

// ---- graph preprocessing -------------------------------------------------

__global__ void k_deg(const int* __restrict__ dst, const float* __restrict__ ew,
                      float* __restrict__ deg, int* __restrict__ cnt) {
    int e = blockIdx.x * 256 + threadIdx.x;
    if (e < E_) {
        int d = dst[e];
        atomicAdd(&deg[d], ew[e]);
        atomicAdd(&cnt[d], 1);
    }
}

// dis + exclusive scan of cnt -> offs/cursor (single block)
__global__ void k_scan(const float* __restrict__ deg, const int* __restrict__ cnt,
                       float* __restrict__ dis, int* __restrict__ offs,
                       int* __restrict__ cursor) {
    __shared__ int part[1024];
    int t = threadIdx.x;
    const int CH = 10;
    int base = t * CH;
    int s = 0;
    for (int i = 0; i < CH; i++) {
        int idx = base + i;
        if (idx < N_) {
            s += cnt[idx];
            float d = deg[idx];
            dis[idx] = d > 0.f ? rsqrtf(d) : 0.f;
        }
    }
    part[t] = s;
    __syncthreads();
    for (int off = 1; off < 1024; off <<= 1) {
        int v = 0;
        if (t >= off) v = part[t - off];
        __syncthreads();
        if (t >= off) part[t] += v;
        __syncthreads();
    }
    int run = (t > 0) ? part[t - 1] : 0;
    for (int i = 0; i < CH; i++) {
        int idx = base + i;
        if (idx < N_) {
            offs[idx] = run;
            cursor[idx] = run;
            run += cnt[idx];
        }
    }
    if (t == 1023) offs[N_] = run;
}

// merged: CSR scatter (first E_ threads) + weight transpose/cast (rest)
__global__ void k_scatprep(
        const int* __restrict__ src, const int* __restrict__ dst,
        const float* __restrict__ ew, const float* __restrict__ dis,
        int* __restrict__ cursor, int* __restrict__ ssrc, float* __restrict__ sw,
        const float* __restrict__ Wc, const float* __restrict__ W1,
        const float* __restrict__ W2, const float* __restrict__ x,
        u16* __restrict__ Wct, u16* __restrict__ W1t, u16* __restrict__ W2t,
        u16* __restrict__ xbf) {
    int i = blockIdx.x * 256 + threadIdx.x;
    if (i < E_) {
        int sn = src[i], dn = dst[i];
        float w = -(dis[sn] * ew[i] * dis[dn]);
        int p = atomicAdd(&cursor[dn], 1);
        ssrc[p] = sn;
        sw[p] = w;
        return;
    }
    int j = i - E_;
    if (j < 49152) {
        int nr = j / 192, k = j % 192;
        Wct[j] = f2bf(Wc[k * 256 + nr]);
    } else if (j < 114688) {
        int q = j - 49152;
        int nr = q >> 8, k = q & 255;
        W1t[q] = f2bf(W1[k * 256 + nr]);
    } else if (j < 131072) {
        int q = j - 114688;
        int nr = q >> 8, k = q & 255;
        W2t[q] = f2bf(W2[k * 64 + nr]);
    } else {
        int q = j - 131072;
        if (q < (B_ * N_ * C_) / 4) {
            float4 v = ((const float4*)x)[q];
            uint2 pv = {pack2(v.x, v.y), pack2(v.z, v.w)};
            ((uint2*)xbf)[q] = pv;
        }
    }
}

// bf16 gather SpMM: one wave per (batch, node). b = blockIdx&7 XCD swizzle so
// each XCD's L2 holds only its batch's 1.28 MB slice. 8-edge unroll: 8 gather
// loads in flight per wave; 4 split accumulators for FMA ILP.
// mode==1: O = 2*sum - xin  (fused Tx2 computation)
__global__ __launch_bounds__(256) void k_prop(
        const u16* __restrict__ T, const int* __restrict__ offs,
        const int* __restrict__ ssrc, const float* __restrict__ sw,
        const u16* __restrict__ xin, u16* __restrict__ O, int mode) {
    int w = threadIdx.x >> 6;
    int lane = threadIdx.x & 63;
    int b = blockIdx.x & 7;
    int n = __builtin_amdgcn_readfirstlane((blockIdx.x >> 3) * 4 + w);
    const u16* Tb = T + (size_t)b * (N_ * C_);
    int s = offs[n], e = offs[n + 1];
    float s0 = 0.f, s1 = 0.f, s2 = 0.f, s3 = 0.f;
    int j = s;
    for (; j + 8 <= e; j += 8) {
        int4 ia = *(const int4*)&ssrc[j];
        int4 ib = *(const int4*)&ssrc[j + 4];
        float4 wa = *(const float4*)&sw[j];
        float4 wb = *(const float4*)&sw[j + 4];
        float v0 = bf2f(Tb[(size_t)ia.x * 64 + lane]);
        float v1 = bf2f(Tb[(size_t)ia.y * 64 + lane]);
        float v2 = bf2f(Tb[(size_t)ia.z * 64 + lane]);
        float v3 = bf2f(Tb[(size_t)ia.w * 64 + lane]);
        float v4 = bf2f(Tb[(size_t)ib.x * 64 + lane]);
        float v5 = bf2f(Tb[(size_t)ib.y * 64 + lane]);
        float v6 = bf2f(Tb[(size_t)ib.z * 64 + lane]);
        float v7 = bf2f(Tb[(size_t)ib.w * 64 + lane]);
        s0 += v0 * wa.x; s1 += v1 * wa.y; s2 += v2 * wa.z; s3 += v3 * wa.w;
        s0 += v4 * wb.x; s1 += v5 * wb.y; s2 += v6 * wb.z; s3 += v7 * wb.w;
    }
    if (j + 4 <= e) {
        int4 ia = *(const int4*)&ssrc[j];
        float4 wa = *(const float4*)&sw[j];
        s0 += bf2f(Tb[(size_t)ia.x * 64 + lane]) * wa.x;
        s1 += bf2f(Tb[(size_t)ia.y * 64 + lane]) * wa.y;
        s2 += bf2f(Tb[(size_t)ia.z * 64 + lane]) * wa.z;
        s3 += bf2f(Tb[(size_t)ia.w * 64 + lane]) * wa.w;
        j += 4;
    }
    for (; j < e; ++j) s0 += bf2f(Tb[(size_t)ssrc[j] * 64 + lane]) * sw[j];
    float sum = (s0 + s1) + (s2 + s3);
    size_t g = ((size_t)b * N_ + n) * 64 + lane;
    float v = sum;
    if (mode) v = 2.f * v - bf2f(xin[g]);
    O[g] = f2bf(v);
}

// ---- fused cheb-einsum + MLP, bf16 MFMA, M=64 rows/block -----------------
// XCD-aligned grid: b = blk&7 (matches k_prop's batch placement), nb = blk>>3.
// GEMM1's A operands load DIRECTLY from global (home-XCD L2) — no A0 LDS
// stage, no staging barriers. LDS holds only h (34.3 KB -> 4 blocks/CU).
__global__ __launch_bounds__(256, 4) void k_fused(
        const u16* __restrict__ xbf, const u16* __restrict__ Tx1,
        const u16* __restrict__ Tx2, const u16* __restrict__ Wct,
        const float* __restrict__ bc, const u16* __restrict__ W1t,
        const float* __restrict__ b1, const u16* __restrict__ W2t,
        const float* __restrict__ b2, const float* __restrict__ beta,
        float* __restrict__ out) {
    __shared__ u16 hbuf[64 * HSTRIDE];
    int t = threadIdx.x;
    int b = blockIdx.x & 7;
    int nb = blockIdx.x >> 3;
    int n0 = nb * 64;

    float sp = logf(1.f + expf(beta[0]));
    int lane = t & 63, w = t >> 6;
    int m = lane & 15, quad = lane >> 4;

    // ---- GEMM1: h = A0[64x192] @ Wc[192x256], +bc, swish -> hbuf
    {
        f32x4 acc[4][4] = {};
        bf16x8 bb[3][4];
        const u16* Wp = Wct + (w * 64 + m) * 192 + quad * 8;
#pragma unroll
        for (int nt = 0; nt < 4; ++nt) {
            bb[0][nt] = *(const bf16x8*)(Wp + nt * 16 * 192);
            bb[1][nt] = *(const bf16x8*)(Wp + nt * 16 * 192 + 32);
        }
        // per-mt clamped row pointers (tail block reads row N-1, not stored)
        size_t rbase[4];
#pragma unroll
        for (int mt = 0; mt < 4; ++mt) {
            int n = n0 + mt * 16 + m;
            if (n >= N_) n = N_ - 1;
            rbase[mt] = ((size_t)b * N_ + n) * 64;
        }
#pragma unroll
        for (int kc = 0; kc < 6; ++kc) {
            if (kc + 2 < 6) {
#pragma unroll
                for (int nt = 0; nt < 4; ++nt)
                    bb[(kc + 2) % 3][nt] =
                        *(const bf16x8*)(Wp + nt * 16 * 192 + (kc + 2) * 32);
            }
            const u16* Asrc = (kc < 2) ? xbf : (kc < 4) ? Tx1 : Tx2;
            int ko = (kc & 1) * 32 + quad * 8;
            bf16x8 a0 = *(const bf16x8*)(Asrc + rbase[0] + ko);
            bf16x8 a1 = *(const bf16x8*)(Asrc + rbase[1] + ko);
            bf16x8 a2 = *(const bf16x8*)(Asrc + rbase[2] + ko);
            bf16x8 a3 = *(const bf16x8*)(Asrc + rbase[3] + ko);
#pragma unroll
            for (int nt = 0; nt < 4; ++nt) {
                acc[0][nt] = MFMA16(a0, bb[kc % 3][nt], acc[0][nt]);
                acc[1][nt] = MFMA16(a1, bb[kc % 3][nt], acc[1][nt]);
                acc[2][nt] = MFMA16(a2, bb[kc % 3][nt], acc[2][nt]);
                acc[3][nt] = MFMA16(a3, bb[kc % 3][nt], acc[3][nt]);
            }
        }
#pragma unroll
        for (int mt = 0; mt < 4; ++mt)
#pragma unroll
            for (int nt = 0; nt < 4; ++nt) {
                int col = w * 64 + nt * 16 + m;
                float bcv = bc[col];
#pragma unroll
                for (int i = 0; i < 4; ++i) {
                    int row = mt * 16 + quad * 4 + i;
                    hbuf[row * HSTRIDE + col] = f2bf(swish_f(acc[mt][nt][i] + bcv, sp));
                }
            }
    }
    __syncthreads();

    // ---- GEMM2: h2 = h[64x256] @ W1[256x256], +b1, swish -> hbuf (in place)
    {
        f32x4 acc[4][4] = {};
        bf16x8 bb[3][4];
        const u16* Wp = W1t + (w * 64 + m) * 256 + quad * 8;
#pragma unroll
        for (int nt = 0; nt < 4; ++nt) {
            bb[0][nt] = *(const bf16x8*)(Wp + nt * 16 * 256);
            bb[1][nt] = *(const bf16x8*)(Wp + nt * 16 * 256 + 32);
        }
#pragma unroll
        for (int kc = 0; kc < 8; ++kc) {
            if (kc + 2 < 8) {
#pragma unroll
                for (int nt = 0; nt < 4; ++nt)
                    bb[(kc + 2) % 3][nt] =
                        *(const bf16x8*)(Wp + nt * 16 * 256 + (kc + 2) * 32);
            }
            int koff = kc * 32 + quad * 8;
            bf16x8 a0 = *(const bf16x8*)&hbuf[m * HSTRIDE + koff];
            bf16x8 a1 = *(const bf16x8*)&hbuf[(16 + m) * HSTRIDE + koff];
            bf16x8 a2 = *(const bf16x8*)&hbuf[(32 + m) * HSTRIDE + koff];
            bf16x8 a3 = *(const bf16x8*)&hbuf[(48 + m) * HSTRIDE + koff];
#pragma unroll
            for (int nt = 0; nt < 4; ++nt) {
                acc[0][nt] = MFMA16(a0, bb[kc % 3][nt], acc[0][nt]);
                acc[1][nt] = MFMA16(a1, bb[kc % 3][nt], acc[1][nt]);
                acc[2][nt] = MFMA16(a2, bb[kc % 3][nt], acc[2][nt]);
                acc[3][nt] = MFMA16(a3, bb[kc % 3][nt], acc[3][nt]);
            }
        }
        __syncthreads();  // all h reads complete before in-place overwrite
#pragma unroll
        for (int mt = 0; mt < 4; ++mt)
#pragma unroll
            for (int nt = 0; nt < 4; ++nt) {
                int col = w * 64 + nt * 16 + m;
                float b1v = b1[col];
#pragma unroll
                for (int i = 0; i < 4; ++i) {
                    int row = mt * 16 + quad * 4 + i;
                    hbuf[row * HSTRIDE + col] = f2bf(swish_f(acc[mt][nt][i] + b1v, sp));
                }
            }
    }
    __syncthreads();

    // ---- GEMM3: Fx = h2[64x256] @ W2[256x64], +b2; out = Fx + x, Fx
    {
        f32x4 acc3[4] = {};
        bf16x8 ball[8];
        const u16* Wp = W2t + (w * 16 + m) * 256 + quad * 8;
#pragma unroll
        for (int kc = 0; kc < 8; ++kc) ball[kc] = *(const bf16x8*)(Wp + kc * 32);
#pragma unroll
        for (int kc = 0; kc < 8; ++kc) {
            int koff = kc * 32 + quad * 8;
            bf16x8 a0 = *(const bf16x8*)&hbuf[m * HSTRIDE + koff];
            bf16x8 a1 = *(const bf16x8*)&hbuf[(16 + m) * HSTRIDE + koff];
            bf16x8 a2 = *(const bf16x8*)&hbuf[(32 + m) * HSTRIDE + koff];
            bf16x8 a3 = *(const bf16x8*)&hbuf[(48 + m) * HSTRIDE + koff];
            acc3[0] = MFMA16(a0, ball[kc], acc3[0]);
            acc3[1] = MFMA16(a1, ball[kc], acc3[1]);
            acc3[2] = MFMA16(a2, ball[kc], acc3[2]);
            acc3[3] = MFMA16(a3, ball[kc], acc3[3]);
        }
        int col = w * 16 + m;
        float b2v = b2[col];
#pragma unroll
        for (int mt = 0; mt < 4; ++mt)
#pragma unroll
            for (int i = 0; i < 4; ++i) {
                int row = mt * 16 + quad * 4 + i;
                int n = n0 + row;
                if (n < N_) {
                    size_t g = ((size_t)b * N_ + n) * 64 + col;
                    float f = acc3[mt][i] + b2v;
                    out[g] = f + bf2f(xbf[g]);
                    out[OUT_OFF_ + g] = f;
                }
            }
    }
}

extern "C" void kernel_launch(void* const* d_in, const int* in_sizes, int n_in,
                              void* d_out, int out_size, void* d_ws, size_t ws_size,
                              hipStream_t stream) {
    const float* x    = (const float*)d_in[0];
    const float* ew   = (const float*)d_in[1];
    const float* Wc   = (const float*)d_in[2];
    const float* bc   = (const float*)d_in[3];
    const float* W1   = (const float*)d_in[4];
    const float* b1   = (const float*)d_in[5];
    const float* W2   = (const float*)d_in[6];
    const float* b2   = (const float*)d_in[7];
    const float* beta = (const float*)d_in[8];
    const int*   ei   = (const int*)d_in[9];
    const int* src = ei;
    const int* dst = ei + E_;
    float* out = (float*)d_out;

    // workspace layout (float units); deg+cnt adjacent for single memset
    float* ws = (float*)d_ws;
    float* deg    = ws + 0;                 // N
    int*   cnt    = (int*)(ws + 10000);     // N
    float* dis    = ws + 20000;             // N
    int*   offs   = (int*)(ws + 30000);     // N+1 (pad to 10008)
    int*   cursor = (int*)(ws + 40008);     // N
    int*   ssrc   = (int*)(ws + 50008);     // E
    float* sw     = ws + 210008;            // E
    u16*   xbf    = (u16*)(ws + 370008);    // B*N*C u16
    u16*   Tx1    = (u16*)(ws + 2930008);   // B*N*C u16
    u16*   Tx2    = (u16*)(ws + 5490008);   // B*N*C u16
    u16*   Wct    = (u16*)(ws + 8050008);   // 49152 u16
    u16*   W1t    = (u16*)(ws + 8074584);   // 65536 u16
    u16*   W2t    = (u16*)(ws + 8107352);   // 16384 u16

    hipMemsetAsync(ws, 0, 2 * (size_t)N_ * sizeof(float), stream);  // deg+cnt

    k_deg<<<(E_ + 255) / 256, 256, 0, stream>>>(dst, ew, deg, cnt);
    k_scan<<<1, 1024, 0, stream>>>(deg, cnt, dis, offs, cursor);
    k_scatprep<<<(E_ + 131072 + (B_ * N_ * C_) / 4 + 255) / 256, 256, 0, stream>>>(
        src, dst, ew, dis, cursor, ssrc, sw, Wc, W1, W2, x, Wct, W1t, W2t, xbf);
    k_prop<<<N_ / 4 * 8, 256, 0, stream>>>(xbf, offs, ssrc, sw, xbf, Tx1, 0);
    k_prop<<<N_ / 4 * 8, 256, 0, stream>>>(Tx1, offs, ssrc, sw, xbf, Tx2, 1);
    k_fused<<<NBLK_ * 8, 256, 0, stream>>>(xbf, Tx1, Tx2, Wct, bc, W1t, b1,
                                           W2t, b2, beta, out);
}

// Round 8
// 265.032 us; speedup vs baseline: 1.0257x; 1.0257x over previous
//
#include <hip/hip_runtime.h>
#include <cstdint>
#include <cstddef>

#define B_ 8
#define N_ 10000
#define C_ 64
#define DIM_ 256
#define E_ 160000
#define ROWS_ (B_ * N_)            // 80000
#define OUT_OFF_ ((size_t)B_ * N_ * C_)  // 5,120,000
#define NBLK_ 157                  // ceil(N/64)

typedef unsigned short u16;
typedef unsigned int u32;
typedef __attribute__((ext_vector_type(8))) short bf16x8;
typedef __attribute__((ext_vector_type(4))) float f32x4;

#define HSTRIDE 268  // u16; 134 dwords == 6 mod 32

__device__ __forceinline__ u16 f2bf(float f) {
    unsigned int u = __float_as_uint(f);
    unsigned int r = u + 0x7FFF + ((u >> 16) & 1);  // RNE
    return (u16)(r >> 16);
}
__device__ __forceinline__ float bf2f(u32 h) {      // low 16 bits hold bf16
    return __uint_as_float(h << 16);
}
__device__ __forceinline__ unsigned int pack2(float a, float b) {
    return (unsigned int)f2bf(a) | ((unsigned int)f2bf(b) << 16);
}
__device__ __forceinline__ float swish_f(float v, float sp) {
    float e = __expf(-v * sp);
    float s = __builtin_amdgcn_rcpf(1.0f + e);
    return v * s * (1.0f / 1.1f);
}

#define MFMA16(a, b, c) __builtin_amdgcn_mfma_f32_16x16x32_bf16(a, b, c, 0, 0, 0)

// ---- graph preprocessing -------------------------------------------------

__global__ void k_deg(const int* __restrict__ dst, const float* __restrict__ ew,
                      float* __restrict__ deg, int* __restrict__ cnt) {
    int e = blockIdx.x * 256 + threadIdx.x;
    if (e < E_) {
        int d = dst[e];
        atomicAdd(&deg[d], ew[e]);
        atomicAdd(&cnt[d], 1);
    }
}

// dis + exclusive scan of cnt -> offs/cursor (single block)
__global__ void k_scan(const float* __restrict__ deg, const int* __restrict__ cnt,
                       float* __restrict__ dis, int* __restrict__ offs,
                       int* __restrict__ cursor) {
    __shared__ int part[1024];
    int t = threadIdx.x;
    const int CH = 10;
    int base = t * CH;
    int s = 0;
    for (int i = 0; i < CH; i++) {
        int idx = base + i;
        if (idx < N_) {
            s += cnt[idx];
            float d = deg[idx];
            dis[idx] = d > 0.f ? rsqrtf(d) : 0.f;
        }
    }
    part[t] = s;
    __syncthreads();
    for (int off = 1; off < 1024; off <<= 1) {
        int v = 0;
        if (t >= off) v = part[t - off];
        __syncthreads();
        if (t >= off) part[t] += v;
        __syncthreads();
    }
    int run = (t > 0) ? part[t - 1] : 0;
    for (int i = 0; i < CH; i++) {
        int idx = base + i;
        if (idx < N_) {
            offs[idx] = run;
            cursor[idx] = run;
            run += cnt[idx];
        }
    }
    if (t == 1023) offs[N_] = run;
}

// merged: CSR scatter (first E_ threads) + weight transpose/cast (rest)
__global__ void k_scatprep(
        const int* __restrict__ src, const int* __restrict__ dst,
        const float* __restrict__ ew, const float* __restrict__ dis,
        int* __restrict__ cursor, int* __restrict__ ssrc, float* __restrict__ sw,
        const float* __restrict__ Wc, const float* __restrict__ W1,
        const float* __restrict__ W2, const float* __restrict__ x,
        u16* __restrict__ Wct, u16* __restrict__ W1t, u16* __restrict__ W2t,
        u16* __restrict__ xbf) {
    int i = blockIdx.x * 256 + threadIdx.x;
    if (i < E_) {
        int sn = src[i], dn = dst[i];
        float w = -(dis[sn] * ew[i] * dis[dn]);
        int p = atomicAdd(&cursor[dn], 1);
        ssrc[p] = sn;
        sw[p] = w;
        return;
    }
    int j = i - E_;
    if (j < 49152) {
        int nr = j / 192, k = j % 192;
        Wct[j] = f2bf(Wc[k * 256 + nr]);
    } else if (j < 114688) {
        int q = j - 49152;
        int nr = q >> 8, k = q & 255;
        W1t[q] = f2bf(W1[k * 256 + nr]);
    } else if (j < 131072) {
        int q = j - 114688;
        int nr = q >> 8, k = q & 255;
        W2t[q] = f2bf(W2[k * 64 + nr]);
    } else {
        int q = j - 131072;
        if (q < (B_ * N_ * C_) / 4) {
            float4 v = ((const float4*)x)[q];
            uint2 pv = {pack2(v.x, v.y), pack2(v.z, v.w)};
            ((uint2*)xbf)[q] = pv;
        }
    }
}

// bf16 gather SpMM: one wave per (batch-PAIR, node). pair = blk&3 -> XCDs
// {p, p+4}; working set 2x1.28 MB fits one XCD L2. 16 gathers in flight per
// 8-edge iteration; index/weight loads amortized over 2 batches.
// mode==1: O = 2*sum - xin  (fused Tx2 computation)
__global__ __launch_bounds__(256) void k_prop(
        const u16* __restrict__ T, const int* __restrict__ offs,
        const int* __restrict__ ssrc, const float* __restrict__ sw,
        const u16* __restrict__ xin, u16* __restrict__ O, int mode) {
    int w = threadIdx.x >> 6;
    int lane = threadIdx.x & 63;
    int p = blockIdx.x & 3;
    int n = __builtin_amdgcn_readfirstlane((blockIdx.x >> 2) * 4 + w);
    const u16* T0 = T + (size_t)p * (N_ * C_);
    const u16* T1 = T + (size_t)(p + 4) * (N_ * C_);
    int s = offs[n], e = offs[n + 1];
    float a0 = 0.f, a1 = 0.f, a2 = 0.f, a3 = 0.f;
    float c0 = 0.f, c1 = 0.f, c2 = 0.f, c3 = 0.f;
    int j = s;
    for (; j + 8 <= e; j += 8) {
        int4 ia = *(const int4*)&ssrc[j];
        int4 ib = *(const int4*)&ssrc[j + 4];
        float4 wa = *(const float4*)&sw[j];
        float4 wb = *(const float4*)&sw[j + 4];
        size_t o0 = (size_t)ia.x * 64 + lane, o1 = (size_t)ia.y * 64 + lane;
        size_t o2 = (size_t)ia.z * 64 + lane, o3 = (size_t)ia.w * 64 + lane;
        size_t o4 = (size_t)ib.x * 64 + lane, o5 = (size_t)ib.y * 64 + lane;
        size_t o6 = (size_t)ib.z * 64 + lane, o7 = (size_t)ib.w * 64 + lane;
        float u0 = bf2f(T0[o0]), v0 = bf2f(T1[o0]);
        float u1 = bf2f(T0[o1]), v1 = bf2f(T1[o1]);
        float u2 = bf2f(T0[o2]), v2 = bf2f(T1[o2]);
        float u3 = bf2f(T0[o3]), v3 = bf2f(T1[o3]);
        float u4 = bf2f(T0[o4]), v4 = bf2f(T1[o4]);
        float u5 = bf2f(T0[o5]), v5 = bf2f(T1[o5]);
        float u6 = bf2f(T0[o6]), v6 = bf2f(T1[o6]);
        float u7 = bf2f(T0[o7]), v7 = bf2f(T1[o7]);
        a0 += u0 * wa.x; c0 += v0 * wa.x;
        a1 += u1 * wa.y; c1 += v1 * wa.y;
        a2 += u2 * wa.z; c2 += v2 * wa.z;
        a3 += u3 * wa.w; c3 += v3 * wa.w;
        a0 += u4 * wb.x; c0 += v4 * wb.x;
        a1 += u5 * wb.y; c1 += v5 * wb.y;
        a2 += u6 * wb.z; c2 += v6 * wb.z;
        a3 += u7 * wb.w; c3 += v7 * wb.w;
    }
    if (j + 4 <= e) {
        int4 ia = *(const int4*)&ssrc[j];
        float4 wa = *(const float4*)&sw[j];
        size_t o0 = (size_t)ia.x * 64 + lane, o1 = (size_t)ia.y * 64 + lane;
        size_t o2 = (size_t)ia.z * 64 + lane, o3 = (size_t)ia.w * 64 + lane;
        a0 += bf2f(T0[o0]) * wa.x; c0 += bf2f(T1[o0]) * wa.x;
        a1 += bf2f(T0[o1]) * wa.y; c1 += bf2f(T1[o1]) * wa.y;
        a2 += bf2f(T0[o2]) * wa.z; c2 += bf2f(T1[o2]) * wa.z;
        a3 += bf2f(T0[o3]) * wa.w; c3 += bf2f(T1[o3]) * wa.w;
        j += 4;
    }
    for (; j < e; ++j) {
        size_t o0 = (size_t)ssrc[j] * 64 + lane;
        float wj = sw[j];
        a0 += bf2f(T0[o0]) * wj;
        c0 += bf2f(T1[o0]) * wj;
    }
    float sum0 = (a0 + a1) + (a2 + a3);
    float sum1 = (c0 + c1) + (c2 + c3);
    size_t g0 = ((size_t)p * N_ + n) * 64 + lane;
    size_t g1 = ((size_t)(p + 4) * N_ + n) * 64 + lane;
    if (mode) {
        sum0 = 2.f * sum0 - bf2f(xin[g0]);
        sum1 = 2.f * sum1 - bf2f(xin[g1]);
    }
    O[g0] = f2bf(sum0);
    O[g1] = f2bf(sum1);
}

// ---- fused cheb-einsum + MLP, bf16 MFMA, M=64 rows/block -----------------
// XCD-aligned (b = blk&7 matches k_prop placement) + coalesced LDS staging of
// A0 (stride 200), h/h2 in place (stride 268). Residual x read from the staged
// A0 in LDS before the overwrite barrier. 34.3 KB LDS -> 4 blocks/CU.
__global__ __launch_bounds__(256, 4) void k_fused(
        const u16* __restrict__ xbf, const u16* __restrict__ Tx1,
        const u16* __restrict__ Tx2, const u16* __restrict__ Wct,
        const float* __restrict__ bc, const u16* __restrict__ W1t,
        const float* __restrict__ b1, const u16* __restrict__ W2t,
        const float* __restrict__ b2, const float* __restrict__ beta,
        float* __restrict__ out) {
    __shared__ u16 buf[64 * HSTRIDE];
    int t = threadIdx.x;
    int b = blockIdx.x & 7;
    int nb = blockIdx.x >> 3;
    int n0 = nb * 64;

    // stage A0 = [x | Tx1 | Tx2] bf16, K-stride 200 (coalesced 8 B/lane loads)
    {
        size_t base = ((size_t)b * N_ + n0) * 16;  // uint2 units (16 per row)
        const uint2* xb = (const uint2*)xbf + base;
        const uint2* tb = (const uint2*)Tx1 + base;
        const uint2* pb = (const uint2*)Tx2 + base;
#pragma unroll
        for (int rep = 0; rep < 4; ++rep) {
            int p = t + rep * 256;
            int r = p >> 4, c4 = p & 15;
            *(uint2*)&buf[r * 200 + c4 * 4] = xb[p];
            *(uint2*)&buf[r * 200 + 64 + c4 * 4] = tb[p];
            *(uint2*)&buf[r * 200 + 128 + c4 * 4] = pb[p];
        }
    }
    __syncthreads();

    float sp = logf(1.f + expf(beta[0]));
    int lane = t & 63, w = t >> 6;
    int m = lane & 15, quad = lane >> 4;
    float xres[4][4];

    // ---- GEMM1: h = A0[64x192] @ Wc[192x256], +bc, swish -> buf (in place)
    {
        f32x4 acc[4][4] = {};
        bf16x8 bb[3][4];
        const u16* Wp = Wct + (w * 64 + m) * 192 + quad * 8;
#pragma unroll
        for (int nt = 0; nt < 4; ++nt) {
            bb[0][nt] = *(const bf16x8*)(Wp + nt * 16 * 192);
            bb[1][nt] = *(const bf16x8*)(Wp + nt * 16 * 192 + 32);
        }
#pragma unroll
        for (int kc = 0; kc < 6; ++kc) {
            if (kc + 2 < 6) {
#pragma unroll
                for (int nt = 0; nt < 4; ++nt)
                    bb[(kc + 2) % 3][nt] =
                        *(const bf16x8*)(Wp + nt * 16 * 192 + (kc + 2) * 32);
            }
            int koff = kc * 32 + quad * 8;
            bf16x8 a0 = *(const bf16x8*)&buf[m * 200 + koff];
            bf16x8 a1 = *(const bf16x8*)&buf[(16 + m) * 200 + koff];
            bf16x8 a2 = *(const bf16x8*)&buf[(32 + m) * 200 + koff];
            bf16x8 a3 = *(const bf16x8*)&buf[(48 + m) * 200 + koff];
#pragma unroll
            for (int nt = 0; nt < 4; ++nt) {
                acc[0][nt] = MFMA16(a0, bb[kc % 3][nt], acc[0][nt]);
                acc[1][nt] = MFMA16(a1, bb[kc % 3][nt], acc[1][nt]);
                acc[2][nt] = MFMA16(a2, bb[kc % 3][nt], acc[2][nt]);
                acc[3][nt] = MFMA16(a3, bb[kc % 3][nt], acc[3][nt]);
            }
        }
        // residual x for GEMM3 epilogue (read-only phase: before barrier)
#pragma unroll
        for (int mt = 0; mt < 4; ++mt)
#pragma unroll
            for (int i = 0; i < 4; ++i)
                xres[mt][i] = bf2f(buf[(mt * 16 + quad * 4 + i) * 200 + w * 16 + m]);
        __syncthreads();  // all A0 reads complete before in-place overwrite
#pragma unroll
        for (int mt = 0; mt < 4; ++mt)
#pragma unroll
            for (int nt = 0; nt < 4; ++nt) {
                int col = w * 64 + nt * 16 + m;
                float bcv = bc[col];
#pragma unroll
                for (int i = 0; i < 4; ++i) {
                    int row = mt * 16 + quad * 4 + i;
                    buf[row * HSTRIDE + col] = f2bf(swish_f(acc[mt][nt][i] + bcv, sp));
                }
            }
    }
    __syncthreads();

    // ---- GEMM2: h2 = h[64x256] @ W1[256x256], +b1, swish -> buf (in place)
    {
        f32x4 acc[4][4] = {};
        bf16x8 bb[3][4];
        const u16* Wp = W1t + (w * 64 + m) * 256 + quad * 8;
#pragma unroll
        for (int nt = 0; nt < 4; ++nt) {
            bb[0][nt] = *(const bf16x8*)(Wp + nt * 16 * 256);
            bb[1][nt] = *(const bf16x8*)(Wp + nt * 16 * 256 + 32);
        }
#pragma unroll
        for (int kc = 0; kc < 8; ++kc) {
            if (kc + 2 < 8) {
#pragma unroll
                for (int nt = 0; nt < 4; ++nt)
                    bb[(kc + 2) % 3][nt] =
                        *(const bf16x8*)(Wp + nt * 16 * 256 + (kc + 2) * 32);
            }
            int koff = kc * 32 + quad * 8;
            bf16x8 a0 = *(const bf16x8*)&buf[m * HSTRIDE + koff];
            bf16x8 a1 = *(const bf16x8*)&buf[(16 + m) * HSTRIDE + koff];
            bf16x8 a2 = *(const bf16x8*)&buf[(32 + m) * HSTRIDE + koff];
            bf16x8 a3 = *(const bf16x8*)&buf[(48 + m) * HSTRIDE + koff];
#pragma unroll
            for (int nt = 0; nt < 4; ++nt) {
                acc[0][nt] = MFMA16(a0, bb[kc % 3][nt], acc[0][nt]);
                acc[1][nt] = MFMA16(a1, bb[kc % 3][nt], acc[1][nt]);
                acc[2][nt] = MFMA16(a2, bb[kc % 3][nt], acc[2][nt]);
                acc[3][nt] = MFMA16(a3, bb[kc % 3][nt], acc[3][nt]);
            }
        }
        __syncthreads();  // all h reads complete before in-place overwrite
#pragma unroll
        for (int mt = 0; mt < 4; ++mt)
#pragma unroll
            for (int nt = 0; nt < 4; ++nt) {
                int col = w * 64 + nt * 16 + m;
                float b1v = b1[col];
#pragma unroll
                for (int i = 0; i < 4; ++i) {
                    int row = mt * 16 + quad * 4 + i;
                    buf[row * HSTRIDE + col] = f2bf(swish_f(acc[mt][nt][i] + b1v, sp));
                }
            }
    }
    __syncthreads();

    // ---- GEMM3: Fx = h2[64x256] @ W2[256x64], +b2; out = Fx + x, Fx
    {
        f32x4 acc3[4] = {};
        bf16x8 ball[8];
        const u16* Wp = W2t + (w * 16 + m) * 256 + quad * 8;
#pragma unroll
        for (int kc = 0; kc < 8; ++kc) ball[kc] = *(const bf16x8*)(Wp + kc * 32);
#pragma unroll
        for (int kc = 0; kc < 8; ++kc) {
            int koff = kc * 32 + quad * 8;
            bf16x8 a0 = *(const bf16x8*)&buf[m * HSTRIDE + koff];
            bf16x8 a1 = *(const bf16x8*)&buf[(16 + m) * HSTRIDE + koff];
            bf16x8 a2 = *(const bf16x8*)&buf[(32 + m) * HSTRIDE + koff];
            bf16x8 a3 = *(const bf16x8*)&buf[(48 + m) * HSTRIDE + koff];
            acc3[0] = MFMA16(a0, ball[kc], acc3[0]);
            acc3[1] = MFMA16(a1, ball[kc], acc3[1]);
            acc3[2] = MFMA16(a2, ball[kc], acc3[2]);
            acc3[3] = MFMA16(a3, ball[kc], acc3[3]);
        }
        int col = w * 16 + m;
        float b2v = b2[col];
#pragma unroll
        for (int mt = 0; mt < 4; ++mt)
#pragma unroll
            for (int i = 0; i < 4; ++i) {
                int row = mt * 16 + quad * 4 + i;
                int n = n0 + row;
                if (n < N_) {
                    size_t g = ((size_t)b * N_ + n) * 64 + col;
                    float f = acc3[mt][i] + b2v;
                    out[g] = f + xres[mt][i];
                    out[OUT_OFF_ + g] = f;
                }
            }
    }
}

extern "C" void kernel_launch(void* const* d_in, const int* in_sizes, int n_in,
                              void* d_out, int out_size, void* d_ws, size_t ws_size,
                              hipStream_t stream) {
    const float* x    = (const float*)d_in[0];
    const float* ew   = (const float*)d_in[1];
    const float* Wc   = (const float*)d_in[2];
    const float* bc   = (const float*)d_in[3];
    const float* W1   = (const float*)d_in[4];
    const float* b1   = (const float*)d_in[5];
    const float* W2   = (const float*)d_in[6];
    const float* b2   = (const float*)d_in[7];
    const float* beta = (const float*)d_in[8];
    const int*   ei   = (const int*)d_in[9];
    const int* src = ei;
    const int* dst = ei + E_;
    float* out = (float*)d_out;

    // workspace layout (float units); deg+cnt adjacent for single memset
    float* ws = (float*)d_ws;
    float* deg    = ws + 0;                 // N
    int*   cnt    = (int*)(ws + 10000);     // N
    float* dis    = ws + 20000;             // N
    int*   offs   = (int*)(ws + 30000);     // N+1 (pad to 10008)
    int*   cursor = (int*)(ws + 40008);     // N
    int*   ssrc   = (int*)(ws + 50008);     // E
    float* sw     = ws + 210008;            // E
    u16*   xbf    = (u16*)(ws + 370008);    // B*N*C u16
    u16*   Tx1    = (u16*)(ws + 2930008);   // B*N*C u16
    u16*   Tx2    = (u16*)(ws + 5490008);   // B*N*C u16
    u16*   Wct    = (u16*)(ws + 8050008);   // 49152 u16
    u16*   W1t    = (u16*)(ws + 8074584);   // 65536 u16
    u16*   W2t    = (u16*)(ws + 8107352);   // 16384 u16

    hipMemsetAsync(ws, 0, 2 * (size_t)N_ * sizeof(float), stream);  // deg+cnt

    k_deg<<<(E_ + 255) / 256, 256, 0, stream>>>(dst, ew, deg, cnt);
    k_scan<<<1, 1024, 0, stream>>>(deg, cnt, dis, offs, cursor);
    k_scatprep<<<(E_ + 131072 + (B_ * N_ * C_) / 4 + 255) / 256, 256, 0, stream>>>(
        src, dst, ew, dis, cursor, ssrc, sw, Wc, W1, W2, x, Wct, W1t, W2t, xbf);
    k_prop<<<N_ / 4 * 4, 256, 0, stream>>>(xbf, offs, ssrc, sw, xbf, Tx1, 0);
    k_prop<<<N_ / 4 * 4, 256, 0, stream>>>(Tx1, offs, ssrc, sw, xbf, Tx2, 1);
    k_fused<<<NBLK_ * 8, 256, 0, stream>>>(xbf, Tx1, Tx2, Wct, bc, W1t, b1,
                                           W2t, b2, beta, out);
}